// Round 5
// baseline (10410.033 us; speedup 1.0000x reference)
//
#include <hip/hip_runtime.h>
#include <hip/hip_bf16.h>
#include <stdint.h>

// LSTM (T=1024, B=64, D=512, H=512) on gfx950.
// Phase 1: X[t,b,n] = inputs @ Wx (packed, bf16 MFMA), n = h*4 + gate.
// Phase 2: 8 teams of 8 WGs; team g owns batch rows [8g,8g+8) (independent in
//   the recurrence). Teams formed adaptively from HW_REG_XCC_ID; local teams
//   exchange H through the XCD-shared L2 (plain stores + first-touch loads on
//   a per-t history buffer) and poll arrive-flags with sc0 loads (L1-bypass,
//   L2-served; agent-scope rescue load every 64 spins guarantees progress).
//   Mixed teams fall back to the proven device-scope protocol. No
//   threadfence/wbl2 anywhere.

typedef float    f32x4  __attribute__((ext_vector_type(4)));
typedef short    s16x8  __attribute__((ext_vector_type(8)));
typedef unsigned short u16;
typedef u16      u16x4  __attribute__((ext_vector_type(4)));
typedef unsigned int u32;

#define TT 1024
#define BB 64
#define DD 512
#define HH 512
#define NG 2048   // 4*HH packed gate columns: n = h*4 + g, g in {i,f,o,c}
#define NTEAM 8
#define NSLOT 8
#define NLW 128   // launched WGs for k_lstm; 64 participate

__device__ __forceinline__ u16 f2bf(float f) {
  __hip_bfloat16 h = __float2bfloat16(f);
  union { __hip_bfloat16 b; u16 u; } v; v.b = h; return v.u;
}
__device__ __forceinline__ float bf2f(u16 u) {
  union { unsigned int i; float f; } v; v.i = ((unsigned int)u) << 16; return v.f;
}
__device__ __forceinline__ float sig_fast(float x) {
  return 1.f / (1.f + __expf(-x));
}
__device__ __forceinline__ float tanh_fast(float x) {
  return 1.f - 2.f / (1.f + __expf(2.f * x));
}

__device__ __forceinline__ void gload_lds16(const u16* g, u16* l) {
  __builtin_amdgcn_global_load_lds(
      (const __attribute__((address_space(1))) unsigned int*)g,
      (__attribute__((address_space(3))) unsigned int*)l, 16, 0, 0);
}

__device__ __forceinline__ void st_plain(u32* p, u32 v) {
  asm volatile("global_store_dword %0, %1, off" :: "v"(p), "v"(v) : "memory");
}
// L1-bypass, L2-served load (SE scope)
__device__ __forceinline__ u32 ld_sc0(const u32* p) {
  u32 v;
  asm volatile("global_load_dword %0, %1, off sc0\n\ts_waitcnt vmcnt(0)"
               : "=v"(v) : "v"(p) : "memory");
  return v;
}

// ---------------- setup: cast inputs fp32 -> bf16 ----------------
__global__ void k_cast(const float* __restrict__ in, u16* __restrict__ out, long n) {
  long i = ((long)blockIdx.x * blockDim.x + threadIdx.x) * 4;
  if (i >= n) return;
  const float4 v = *(const float4*)(in + i);
  u16x4 o; o.x = f2bf(v.x); o.y = f2bf(v.y); o.z = f2bf(v.z); o.w = f2bf(v.w);
  *(u16x4*)(out + i) = o;
}

// ---------------- setup: pack weights transposed + gate-interleaved ----------------
__global__ void k_pack(const float* __restrict__ Wxi, const float* __restrict__ Whi, const float* __restrict__ bi,
                       const float* __restrict__ Wxf, const float* __restrict__ Whf, const float* __restrict__ bfi,
                       const float* __restrict__ Wxo, const float* __restrict__ Who, const float* __restrict__ bo,
                       const float* __restrict__ Wxc, const float* __restrict__ Whc, const float* __restrict__ bc,
                       u16* __restrict__ WxT, u16* __restrict__ WhT, float* __restrict__ biasp)
{
  const int k = blockIdx.x;  // 0..511
  const float* Wx[4] = {Wxi, Wxf, Wxo, Wxc};
  const float* Wh[4] = {Whi, Whf, Who, Whc};
  for (int h = threadIdx.x; h < HH; h += blockDim.x) {
#pragma unroll
    for (int g = 0; g < 4; ++g) {
      const long n = h * 4 + g;
      WxT[n * DD + k] = f2bf(Wx[g][(long)k * HH + h]);
      WhT[n * HH + k] = f2bf(Wh[g][(long)k * HH + h]);
    }
  }
  if (k == 0) {
    const float* bp[4] = {bi, bfi, bo, bc};
    for (int n = threadIdx.x; n < NG; n += blockDim.x)
      biasp[n] = bp[n & 3][n >> 2];
  }
}

// ---------------- phase 1: X = A(bf16) @ WxT^T + bias, store bf16 ----------------
__global__ __launch_bounds__(256) void k_gemm_x(
    const u16* __restrict__ A, const u16* __restrict__ BT,
    const float* __restrict__ biasp, u16* __restrict__ X)
{
  __shared__ __align__(16) u16 As[128 * 64];
  __shared__ __align__(16) u16 Bs[128 * 64];
  const int tid = threadIdx.x;
  const int l = tid & 63;
  const int w = tid >> 6;
  const int wr = w >> 1, wc = w & 1;
  const long brow = (long)blockIdx.y * 128;
  const int  bcol = blockIdx.x * 128;
  const int  lr = l >> 3, lc = l & 7;
  const int  cl = l & 15, rg = l >> 4;

  f32x4 acc[4][4];
#pragma unroll
  for (int m = 0; m < 4; ++m)
#pragma unroll
    for (int n = 0; n < 4; ++n) acc[m][n] = (f32x4){0.f, 0.f, 0.f, 0.f};

  for (int k0 = 0; k0 < DD; k0 += 64) {
#pragma unroll
    for (int j = 0; j < 4; ++j) {
      const int sub = w * 4 + j;
      gload_lds16(A  + (brow + sub * 8 + lr) * DD + k0 + lc * 8, &As[sub * 512]);
      gload_lds16(BT + ((long)(bcol + sub * 8 + lr)) * DD + k0 + lc * 8, &Bs[sub * 512]);
    }
    __syncthreads();
#pragma unroll
    for (int kk = 0; kk < 2; ++kk) {
      s16x8 af[4], bfr[4];
#pragma unroll
      for (int m = 0; m < 4; ++m)
        af[m] = *(const s16x8*)&As[(wr * 64 + m * 16 + cl) * 64 + kk * 32 + rg * 8];
#pragma unroll
      for (int n = 0; n < 4; ++n)
        bfr[n] = *(const s16x8*)&Bs[(wc * 64 + n * 16 + cl) * 64 + kk * 32 + rg * 8];
#pragma unroll
      for (int m = 0; m < 4; ++m)
#pragma unroll
        for (int n = 0; n < 4; ++n)
          acc[m][n] = __builtin_amdgcn_mfma_f32_16x16x32_bf16(af[m], bfr[n], acc[m][n], 0, 0, 0);
    }
    __syncthreads();
  }
#pragma unroll
  for (int n = 0; n < 4; ++n) {
    const int col = bcol + wc * 64 + n * 16 + cl;
    const float bv = biasp[col];
#pragma unroll
    for (int m = 0; m < 4; ++m)
#pragma unroll
      for (int j = 0; j < 4; ++j) {
        const long row = brow + wr * 64 + m * 16 + rg * 4 + j;
        X[row * NG + col] = f2bf(acc[m][n][j] + bv);
      }
  }
}

// ---------------- phase 2: team-local recurrent kernel ----------------
__global__ __launch_bounds__(512, 2) void k_lstm(
    const u16* __restrict__ X, const u16* __restrict__ WhT,
    u16* __restrict__ Hh, float* __restrict__ Cst,
    float* __restrict__ dout, float* __restrict__ doutH, float* __restrict__ doutC,
    u32* __restrict__ ctl, u32* __restrict__ flags, int t0, int t1)
{
  __shared__ __align__(16) float pre[8][260];
  __shared__ int s_team, s_slot, s_mixed;
  const int tid = threadIdx.x;

  // ---- adaptive team formation (placement-robust, deadlock-free) ----
  if (tid == 0) {
    u32 x;
    asm volatile("s_getreg_b32 %0, hwreg(HW_REG_XCC_ID)" : "=s"(x));
    x &= 7u;
    u32 r = __hip_atomic_fetch_add(&ctl[x], 1u, __ATOMIC_RELAXED, __HIP_MEMORY_SCOPE_AGENT);
    u32 p = 0;
    if (r >= NSLOT)
      p = __hip_atomic_fetch_add(&ctl[8], 1u, __ATOMIC_RELAXED, __HIP_MEMORY_SCOPE_AGENT);
    __hip_atomic_fetch_add(&ctl[9], 1u, __ATOMIC_RELAXED, __HIP_MEMORY_SCOPE_AGENT);
    while (__hip_atomic_load(&ctl[9], __ATOMIC_RELAXED, __HIP_MEMORY_SCOPE_AGENT) < (u32)NLW)
      __builtin_amdgcn_s_sleep(4);
    u32 c[8];
#pragma unroll
    for (int i = 0; i < 8; ++i)
      c[i] = __hip_atomic_load(&ctl[i], __ATOMIC_RELAXED, __HIP_MEMORY_SCOPE_AGENT);
    int team = -1, slot = 0;
    if (r < NSLOT) { team = (int)x; slot = (int)r; }
    else {
      u32 acc = 0;
      for (int tt = 0; tt < 8; ++tt) {
        u32 have = c[tt] < NSLOT ? c[tt] : NSLOT;
        u32 miss = NSLOT - have;
        if (team < 0 && p < acc + miss) { team = tt; slot = (int)(have + (p - acc)); }
        acc += miss;
      }
    }
    s_team = team; s_slot = slot;
    s_mixed = (team >= 0 && c[team] < NSLOT) ? 1 : 0;
  }
  __syncthreads();
  const int team = s_team, slot = s_slot, mixed = s_mixed;
  if (team < 0) return;

  const int l = tid & 63, wv = tid >> 6;
  const int cl = l & 15, rg = l >> 4;
  const int gcol0 = slot * 256 + wv * 32;   // this wave's gate-col base

  // constant B fragments (registers, loaded once)
  s16x8 bfr[2][16];
#pragma unroll
  for (int nt = 0; nt < 2; ++nt)
#pragma unroll
    for (int ks = 0; ks < 16; ++ks)
      bfr[nt][ks] = *(const s16x8*)&WhT[(long)(gcol0 + nt * 16 + cl) * HH + ks * 32 + rg * 8];

  // pointwise ownership: 1 thread = (row, h)
  const int prow = tid >> 6;               // 0..7  (== wv)
  const int phl  = tid & 63;               // 0..63
  const int grow = team * 8 + prow;        // global batch row
  const int ghl  = slot * 64 + phl;        // global h

  float creg;
  if (t0 == 0) creg = 0.f; else creg = Cst[grow * HH + ghl];

  u32* myflag = &flags[(team * 8 + slot) * 32];

  for (int t = t0; t < t1; ++t) {
    const int s = t - t0;
    // X for this step (issued before the poll; read-only, no hazard)
    u16x4 xv = *(const u16x4*)&X[((long)s * BB + grow) * NG + slot * 256 + phl * 4];

    if (t > t0) {                           // all team flags >= t
      if (wv == 0) {
        const u32 tgt = (u32)t;
        u32 vv; unsigned long long b; int it = 0;
        do {
          ++it;
          if (l < NSLOT) {
            u32* fp = &flags[(team * 8 + l) * 32];
            if (!mixed && (it & 63) != 0) vv = ld_sc0(fp);         // L2-served
            else vv = __hip_atomic_load(fp, __ATOMIC_RELAXED,      // rescue/mixed
                                        __HIP_MEMORY_SCOPE_AGENT);
          } else vv = tgt;
          b = __ballot(vv >= tgt);
        } while (b != ~0ULL);
      }
      __syncthreads();
    }

    f32x4 a0a = (f32x4){0.f,0.f,0.f,0.f}, a0b = (f32x4){0.f,0.f,0.f,0.f};
    f32x4 a1a = (f32x4){0.f,0.f,0.f,0.f}, a1b = (f32x4){0.f,0.f,0.f,0.f};
    if (t > 0) {
      const u16* Hp = Hh + (long)(t - 1) * BB * HH;
      s16x8 af[16];
#pragma unroll
      for (int ks = 0; ks < 16; ++ks) af[ks] = (s16x8){0,0,0,0,0,0,0,0};
      if (cl < 8) {
#pragma unroll
        for (int ks = 0; ks < 16; ++ks)
          af[ks] = *(const s16x8*)&Hp[(team * 8 + cl) * HH + ks * 32 + rg * 8];
      }
#pragma unroll
      for (int ks = 0; ks < 16; ks += 2) {   // 4 independent acc chains
        a0a = __builtin_amdgcn_mfma_f32_16x16x32_bf16(af[ks],     bfr[0][ks],     a0a, 0, 0, 0);
        a1a = __builtin_amdgcn_mfma_f32_16x16x32_bf16(af[ks],     bfr[1][ks],     a1a, 0, 0, 0);
        a0b = __builtin_amdgcn_mfma_f32_16x16x32_bf16(af[ks + 1], bfr[0][ks + 1], a0b, 0, 0, 0);
        a1b = __builtin_amdgcn_mfma_f32_16x16x32_bf16(af[ks + 1], bfr[1][ks + 1], a1b, 0, 0, 0);
      }
    }
    const f32x4 acc0 = a0a + a0b, acc1 = a1a + a1b;
    if (rg < 2) {                            // valid output rows 0..7
#pragma unroll
      for (int j = 0; j < 4; ++j) {
        pre[rg * 4 + j][wv * 32 + cl]      = acc0[j];
        pre[rg * 4 + j][wv * 32 + 16 + cl] = acc1[j];
      }
    }
    __syncthreads();

    // pointwise: 4 gates of one h
    f32x4 pv = *(const f32x4*)&pre[prow][phl * 4];
    const float pi = pv[0] + bf2f((u16)xv.x);
    const float pf = pv[1] + bf2f((u16)xv.y);
    const float po = pv[2] + bf2f((u16)xv.z);
    const float pc = pv[3] + bf2f((u16)xv.w);
    const float ig = sig_fast(pi);
    const float fg = sig_fast(pf);
    const float og = sig_fast(po);
    const float ct = tanh_fast(pc);
    creg = fg * creg + ig * ct;
    const float hv = og * tanh_fast(creg);
    const u16 hb = f2bf(hv);
    u16* hdst = &Hh[((long)t * BB + grow) * HH + ghl];
    if (!mixed) *hdst = hb;
    else asm volatile("global_store_short %0, %1, off sc1"
                      :: "v"(hdst), "v"((u32)hb) : "memory");

    // drain H stores, then arrive; dout goes AFTER the flag (off critical path)
    asm volatile("s_waitcnt vmcnt(0)" ::: "memory");
    __syncthreads();
    if (tid == 0) {
      if (!mixed) st_plain(myflag, (u32)(t + 1));
      else __hip_atomic_store(myflag, (u32)(t + 1),
                              __ATOMIC_RELAXED, __HIP_MEMORY_SCOPE_AGENT);
    }
    dout[((long)t * BB + grow) * HH + ghl] = hv;
    if (t == TT - 1) {
      doutH[grow * HH + ghl] = hv;
      doutC[grow * HH + ghl] = creg;
    }
  }

  Cst[grow * HH + ghl] = creg;   // plain; flushed at kernel end
}

// ---------------- host ----------------
extern "C" void kernel_launch(void* const* d_in, const int* in_sizes, int n_in,
                              void* d_out, int out_size, void* d_ws, size_t ws_size,
                              hipStream_t stream)
{
  const float* inputs = (const float*)d_in[0];
  const float* W_xi = (const float*)d_in[1];
  const float* W_hi = (const float*)d_in[2];
  const float* b_i  = (const float*)d_in[3];
  const float* W_xf = (const float*)d_in[4];
  const float* W_hf = (const float*)d_in[5];
  const float* b_f  = (const float*)d_in[6];
  const float* W_xo = (const float*)d_in[7];
  const float* W_ho = (const float*)d_in[8];
  const float* b_o  = (const float*)d_in[9];
  const float* W_xc = (const float*)d_in[10];
  const float* W_hc = (const float*)d_in[11];
  const float* b_c  = (const float*)d_in[12];
  float* out = (float*)d_out;
  char* ws = (char*)d_ws;

  size_t off = 0;
  auto walloc = [&](size_t sz) { size_t o = off; off = (off + sz + 255) & ~(size_t)255; return o; };
  const size_t o_inbf  = walloc((size_t)TT * BB * DD * 2);   // 64 MB
  const size_t o_WxT   = walloc((size_t)NG * DD * 2);        // 2 MB
  const size_t o_WhT   = walloc((size_t)NG * HH * 2);        // 2 MB
  const size_t o_bias  = walloc((size_t)NG * 4);
  const size_t o_C     = walloc((size_t)BB * HH * 4);
  const size_t o_Hh    = walloc((size_t)TT * BB * HH * 2);   // 64 MB history
  const size_t o_ctl   = walloc(256);
  const size_t o_flags = walloc(8192);
  const size_t o_X     = off;

  const size_t bytes_per_step = (size_t)BB * NG * 2;         // 256 KB
  long spc = (ws_size > o_X) ? (long)((ws_size - o_X) / bytes_per_step) : 0;
  if (spc > TT) spc = TT;
  spc &= ~1L;
  if (spc < 2) spc = 2;

  u16*   inbf  = (u16*)(ws + o_inbf);
  u16*   WxT   = (u16*)(ws + o_WxT);
  u16*   WhT   = (u16*)(ws + o_WhT);
  float* biasp = (float*)(ws + o_bias);
  u16*   Xbuf  = (u16*)(ws + o_X);
  u16*   Hh    = (u16*)(ws + o_Hh);
  float* Cst   = (float*)(ws + o_C);

  k_cast<<<dim3((TT * BB * DD) / 1024), dim3(256), 0, stream>>>(inputs, inbf, (long)TT * BB * DD);
  k_pack<<<dim3(DD), dim3(256), 0, stream>>>(W_xi, W_hi, b_i, W_xf, W_hf, b_f,
                                             W_xo, W_ho, b_o, W_xc, W_hc, b_c,
                                             WxT, WhT, biasp);

  float* doutH = out + (size_t)TT * BB * HH;
  float* doutC = doutH + (size_t)BB * HH;

  for (int t0 = 0; t0 < TT; t0 += (int)spc) {
    int t1 = t0 + (int)spc; if (t1 > TT) t1 = TT;
    const int rows = (t1 - t0) * BB;
    k_gemm_x<<<dim3(NG / 128, rows / 128), dim3(256), 0, stream>>>(
        inbf + (size_t)t0 * BB * DD, WxT, biasp, Xbuf);
    hipMemsetAsync(ws + o_ctl, 0, 256, stream);
    hipMemsetAsync(ws + o_flags, 0, 8192, stream);
    k_lstm<<<dim3(NLW), dim3(512), 0, stream>>>(
        Xbuf, WhT, Hh, Cst, out, doutH, doutC,
        (u32*)(ws + o_ctl), (u32*)(ws + o_flags), t0, t1);
  }
}

// Round 6
// 7301.413 us; speedup vs baseline: 1.4258x; 1.4258x over previous
//
#include <hip/hip_runtime.h>
#include <hip/hip_bf16.h>
#include <stdint.h>

// LSTM (T=1024, B=64, D=512, H=512) on gfx950.
// Phase 1: X[t,b,n] = inputs @ Wx (packed, bf16 MFMA), n = h*4 + gate.
// Phase 2: 8 teams of 8 WGs; team g owns batch rows [8g,8g+8) (independent in
//   the recurrence). Teams formed adaptively from HW_REG_XCC_ID; local teams
//   exchange H through the XCD-shared L2 (plain stores + first-touch loads on
//   a per-t history buffer) and poll arrive-flags with sc0 loads (L1-bypass,
//   L2-served) WITH s_sleep backoff between failed polls (R5 lesson: tight
//   sc0 polling congests the L2 sectors the producers' write-through stores
//   must update). Agent-scope rescue load every 16th iteration guarantees
//   progress under any cache behavior. Mixed teams use the proven
//   device-scope protocol. No threadfence/wbl2 anywhere.

typedef float    f32x4  __attribute__((ext_vector_type(4)));
typedef short    s16x8  __attribute__((ext_vector_type(8)));
typedef unsigned short u16;
typedef u16      u16x4  __attribute__((ext_vector_type(4)));
typedef unsigned int u32;

#define TT 1024
#define BB 64
#define DD 512
#define HH 512
#define NG 2048   // 4*HH packed gate columns: n = h*4 + g, g in {i,f,o,c}
#define NTEAM 8
#define NSLOT 8
#define NLW 128   // launched WGs for k_lstm; 64 participate

__device__ __forceinline__ u16 f2bf(float f) {
  __hip_bfloat16 h = __float2bfloat16(f);
  union { __hip_bfloat16 b; u16 u; } v; v.b = h; return v.u;
}
__device__ __forceinline__ float bf2f(u16 u) {
  union { unsigned int i; float f; } v; v.i = ((unsigned int)u) << 16; return v.f;
}
__device__ __forceinline__ float sig_fast(float x) {
  return 1.f / (1.f + __expf(-x));
}
__device__ __forceinline__ float tanh_fast(float x) {
  return 1.f - 2.f / (1.f + __expf(2.f * x));
}

__device__ __forceinline__ void gload_lds16(const u16* g, u16* l) {
  __builtin_amdgcn_global_load_lds(
      (const __attribute__((address_space(1))) unsigned int*)g,
      (__attribute__((address_space(3))) unsigned int*)l, 16, 0, 0);
}

__device__ __forceinline__ void st_plain(u32* p, u32 v) {
  asm volatile("global_store_dword %0, %1, off" :: "v"(p), "v"(v) : "memory");
}
// L1-bypass, L2-served load (SE scope)
__device__ __forceinline__ u32 ld_sc0(const u32* p) {
  u32 v;
  asm volatile("global_load_dword %0, %1, off sc0\n\ts_waitcnt vmcnt(0)"
               : "=v"(v) : "v"(p) : "memory");
  return v;
}

// ---------------- setup: cast inputs fp32 -> bf16 ----------------
__global__ void k_cast(const float* __restrict__ in, u16* __restrict__ out, long n) {
  long i = ((long)blockIdx.x * blockDim.x + threadIdx.x) * 4;
  if (i >= n) return;
  const float4 v = *(const float4*)(in + i);
  u16x4 o; o.x = f2bf(v.x); o.y = f2bf(v.y); o.z = f2bf(v.z); o.w = f2bf(v.w);
  *(u16x4*)(out + i) = o;
}

// ---------------- setup: pack weights transposed + gate-interleaved ----------------
__global__ void k_pack(const float* __restrict__ Wxi, const float* __restrict__ Whi, const float* __restrict__ bi,
                       const float* __restrict__ Wxf, const float* __restrict__ Whf, const float* __restrict__ bfi,
                       const float* __restrict__ Wxo, const float* __restrict__ Who, const float* __restrict__ bo,
                       const float* __restrict__ Wxc, const float* __restrict__ Whc, const float* __restrict__ bc,
                       u16* __restrict__ WxT, u16* __restrict__ WhT, float* __restrict__ biasp)
{
  const int k = blockIdx.x;  // 0..511
  const float* Wx[4] = {Wxi, Wxf, Wxo, Wxc};
  const float* Wh[4] = {Whi, Whf, Who, Whc};
  for (int h = threadIdx.x; h < HH; h += blockDim.x) {
#pragma unroll
    for (int g = 0; g < 4; ++g) {
      const long n = h * 4 + g;
      WxT[n * DD + k] = f2bf(Wx[g][(long)k * HH + h]);
      WhT[n * HH + k] = f2bf(Wh[g][(long)k * HH + h]);
    }
  }
  if (k == 0) {
    const float* bp[4] = {bi, bfi, bo, bc};
    for (int n = threadIdx.x; n < NG; n += blockDim.x)
      biasp[n] = bp[n & 3][n >> 2];
  }
}

// ---------------- phase 1: X = A(bf16) @ WxT^T + bias, store bf16 ----------------
__global__ __launch_bounds__(256) void k_gemm_x(
    const u16* __restrict__ A, const u16* __restrict__ BT,
    const float* __restrict__ biasp, u16* __restrict__ X)
{
  __shared__ __align__(16) u16 As[128 * 64];
  __shared__ __align__(16) u16 Bs[128 * 64];
  const int tid = threadIdx.x;
  const int l = tid & 63;
  const int w = tid >> 6;
  const int wr = w >> 1, wc = w & 1;
  const long brow = (long)blockIdx.y * 128;
  const int  bcol = blockIdx.x * 128;
  const int  lr = l >> 3, lc = l & 7;
  const int  cl = l & 15, rg = l >> 4;

  f32x4 acc[4][4];
#pragma unroll
  for (int m = 0; m < 4; ++m)
#pragma unroll
    for (int n = 0; n < 4; ++n) acc[m][n] = (f32x4){0.f, 0.f, 0.f, 0.f};

  for (int k0 = 0; k0 < DD; k0 += 64) {
#pragma unroll
    for (int j = 0; j < 4; ++j) {
      const int sub = w * 4 + j;
      gload_lds16(A  + (brow + sub * 8 + lr) * DD + k0 + lc * 8, &As[sub * 512]);
      gload_lds16(BT + ((long)(bcol + sub * 8 + lr)) * DD + k0 + lc * 8, &Bs[sub * 512]);
    }
    __syncthreads();
#pragma unroll
    for (int kk = 0; kk < 2; ++kk) {
      s16x8 af[4], bfr[4];
#pragma unroll
      for (int m = 0; m < 4; ++m)
        af[m] = *(const s16x8*)&As[(wr * 64 + m * 16 + cl) * 64 + kk * 32 + rg * 8];
#pragma unroll
      for (int n = 0; n < 4; ++n)
        bfr[n] = *(const s16x8*)&Bs[(wc * 64 + n * 16 + cl) * 64 + kk * 32 + rg * 8];
#pragma unroll
      for (int m = 0; m < 4; ++m)
#pragma unroll
        for (int n = 0; n < 4; ++n)
          acc[m][n] = __builtin_amdgcn_mfma_f32_16x16x32_bf16(af[m], bfr[n], acc[m][n], 0, 0, 0);
    }
    __syncthreads();
  }
#pragma unroll
  for (int n = 0; n < 4; ++n) {
    const int col = bcol + wc * 64 + n * 16 + cl;
    const float bv = biasp[col];
#pragma unroll
    for (int m = 0; m < 4; ++m)
#pragma unroll
      for (int j = 0; j < 4; ++j) {
        const long row = brow + wr * 64 + m * 16 + rg * 4 + j;
        X[row * NG + col] = f2bf(acc[m][n][j] + bv);
      }
  }
}

// ---------------- phase 2: team-local recurrent kernel ----------------
__global__ __launch_bounds__(512, 2) void k_lstm(
    const u16* __restrict__ X, const u16* __restrict__ WhT,
    u16* __restrict__ Hh, float* __restrict__ Cst,
    float* __restrict__ dout, float* __restrict__ doutH, float* __restrict__ doutC,
    u32* __restrict__ ctl, u32* __restrict__ flags, int t0, int t1)
{
  __shared__ __align__(16) float pre[8][260];
  __shared__ int s_team, s_slot, s_mixed;
  const int tid = threadIdx.x;

  // ---- adaptive team formation (placement-robust, deadlock-free) ----
  if (tid == 0) {
    u32 x;
    asm volatile("s_getreg_b32 %0, hwreg(HW_REG_XCC_ID)" : "=s"(x));
    x &= 7u;
    u32 r = __hip_atomic_fetch_add(&ctl[x], 1u, __ATOMIC_RELAXED, __HIP_MEMORY_SCOPE_AGENT);
    u32 p = 0;
    if (r >= NSLOT)
      p = __hip_atomic_fetch_add(&ctl[8], 1u, __ATOMIC_RELAXED, __HIP_MEMORY_SCOPE_AGENT);
    __hip_atomic_fetch_add(&ctl[9], 1u, __ATOMIC_RELAXED, __HIP_MEMORY_SCOPE_AGENT);
    while (__hip_atomic_load(&ctl[9], __ATOMIC_RELAXED, __HIP_MEMORY_SCOPE_AGENT) < (u32)NLW)
      __builtin_amdgcn_s_sleep(4);
    u32 c[8];
#pragma unroll
    for (int i = 0; i < 8; ++i)
      c[i] = __hip_atomic_load(&ctl[i], __ATOMIC_RELAXED, __HIP_MEMORY_SCOPE_AGENT);
    int team = -1, slot = 0;
    if (r < NSLOT) { team = (int)x; slot = (int)r; }
    else {
      u32 acc = 0;
      for (int tt = 0; tt < 8; ++tt) {
        u32 have = c[tt] < NSLOT ? c[tt] : NSLOT;
        u32 miss = NSLOT - have;
        if (team < 0 && p < acc + miss) { team = tt; slot = (int)(have + (p - acc)); }
        acc += miss;
      }
    }
    s_team = team; s_slot = slot;
    s_mixed = (team >= 0 && c[team] < NSLOT) ? 1 : 0;
  }
  __syncthreads();
  const int team = s_team, slot = s_slot, mixed = s_mixed;
  if (team < 0) return;

  const int l = tid & 63, wv = tid >> 6;
  const int cl = l & 15, rg = l >> 4;
  const int gcol0 = slot * 256 + wv * 32;   // this wave's gate-col base

  // constant B fragments (registers, loaded once)
  s16x8 bfr[2][16];
#pragma unroll
  for (int nt = 0; nt < 2; ++nt)
#pragma unroll
    for (int ks = 0; ks < 16; ++ks)
      bfr[nt][ks] = *(const s16x8*)&WhT[(long)(gcol0 + nt * 16 + cl) * HH + ks * 32 + rg * 8];

  // pointwise ownership: 1 thread = (row, h)
  const int prow = tid >> 6;               // 0..7  (== wv)
  const int phl  = tid & 63;               // 0..63
  const int grow = team * 8 + prow;        // global batch row
  const int ghl  = slot * 64 + phl;        // global h

  float creg;
  if (t0 == 0) creg = 0.f; else creg = Cst[grow * HH + ghl];

  u32* myflag = &flags[(team * 8 + slot) * 32];

  for (int t = t0; t < t1; ++t) {
    const int s = t - t0;
    // X for this step (issued before the poll; read-only, no hazard)
    u16x4 xv = *(const u16x4*)&X[((long)s * BB + grow) * NG + slot * 256 + phl * 4];

    if (t > t0) {                           // all team flags >= t
      if (wv == 0) {
        const u32 tgt = (u32)t;
        u32 vv; unsigned long long b; int it = 1;
        for (;;) {
          if (l < NSLOT) {
            u32* fp = &flags[(team * 8 + l) * 32];
            if (!mixed && (it & 15) != 0) vv = ld_sc0(fp);         // L2-served
            else vv = __hip_atomic_load(fp, __ATOMIC_RELAXED,      // rescue/mixed
                                        __HIP_MEMORY_SCOPE_AGENT);
          } else vv = tgt;
          b = __ballot(vv >= tgt);
          if (b == ~0ULL) break;
          ++it;
          __builtin_amdgcn_s_sleep(8);      // ~512cy backoff: don't storm L2
        }
      }
      __syncthreads();
    }

    f32x4 a0a = (f32x4){0.f,0.f,0.f,0.f}, a0b = (f32x4){0.f,0.f,0.f,0.f};
    f32x4 a1a = (f32x4){0.f,0.f,0.f,0.f}, a1b = (f32x4){0.f,0.f,0.f,0.f};
    if (t > 0) {
      const u16* Hp = Hh + (long)(t - 1) * BB * HH;
      s16x8 af[16];
#pragma unroll
      for (int ks = 0; ks < 16; ++ks) af[ks] = (s16x8){0,0,0,0,0,0,0,0};
      if (cl < 8) {
#pragma unroll
        for (int ks = 0; ks < 16; ++ks)
          af[ks] = *(const s16x8*)&Hp[(team * 8 + cl) * HH + ks * 32 + rg * 8];
      }
#pragma unroll
      for (int ks = 0; ks < 16; ks += 2) {   // 4 independent acc chains
        a0a = __builtin_amdgcn_mfma_f32_16x16x32_bf16(af[ks],     bfr[0][ks],     a0a, 0, 0, 0);
        a1a = __builtin_amdgcn_mfma_f32_16x16x32_bf16(af[ks],     bfr[1][ks],     a1a, 0, 0, 0);
        a0b = __builtin_amdgcn_mfma_f32_16x16x32_bf16(af[ks + 1], bfr[0][ks + 1], a0b, 0, 0, 0);
        a1b = __builtin_amdgcn_mfma_f32_16x16x32_bf16(af[ks + 1], bfr[1][ks + 1], a1b, 0, 0, 0);
      }
    }
    const f32x4 acc0 = a0a + a0b, acc1 = a1a + a1b;
    if (rg < 2) {                            // valid output rows 0..7
#pragma unroll
      for (int j = 0; j < 4; ++j) {
        pre[rg * 4 + j][wv * 32 + cl]      = acc0[j];
        pre[rg * 4 + j][wv * 32 + 16 + cl] = acc1[j];
      }
    }
    __syncthreads();

    // pointwise: 4 gates of one h
    f32x4 pv = *(const f32x4*)&pre[prow][phl * 4];
    const float pi = pv[0] + bf2f((u16)xv.x);
    const float pf = pv[1] + bf2f((u16)xv.y);
    const float po = pv[2] + bf2f((u16)xv.z);
    const float pc = pv[3] + bf2f((u16)xv.w);
    const float ig = sig_fast(pi);
    const float fg = sig_fast(pf);
    const float og = sig_fast(po);
    const float ct = tanh_fast(pc);
    creg = fg * creg + ig * ct;
    const float hv = og * tanh_fast(creg);
    const u16 hb = f2bf(hv);
    u16* hdst = &Hh[((long)t * BB + grow) * HH + ghl];
    if (!mixed) *hdst = hb;
    else asm volatile("global_store_short %0, %1, off sc1"
                      :: "v"(hdst), "v"((u32)hb) : "memory");

    // drain H stores, then arrive; dout goes AFTER the flag (off critical path)
    asm volatile("s_waitcnt vmcnt(0)" ::: "memory");
    __syncthreads();
    if (tid == 0) {
      if (!mixed) st_plain(myflag, (u32)(t + 1));
      else __hip_atomic_store(myflag, (u32)(t + 1),
                              __ATOMIC_RELAXED, __HIP_MEMORY_SCOPE_AGENT);
    }
    dout[((long)t * BB + grow) * HH + ghl] = hv;
    if (t == TT - 1) {
      doutH[grow * HH + ghl] = hv;
      doutC[grow * HH + ghl] = creg;
    }
  }

  Cst[grow * HH + ghl] = creg;   // plain; flushed at kernel end
}

// ---------------- host ----------------
extern "C" void kernel_launch(void* const* d_in, const int* in_sizes, int n_in,
                              void* d_out, int out_size, void* d_ws, size_t ws_size,
                              hipStream_t stream)
{
  const float* inputs = (const float*)d_in[0];
  const float* W_xi = (const float*)d_in[1];
  const float* W_hi = (const float*)d_in[2];
  const float* b_i  = (const float*)d_in[3];
  const float* W_xf = (const float*)d_in[4];
  const float* W_hf = (const float*)d_in[5];
  const float* b_f  = (const float*)d_in[6];
  const float* W_xo = (const float*)d_in[7];
  const float* W_ho = (const float*)d_in[8];
  const float* b_o  = (const float*)d_in[9];
  const float* W_xc = (const float*)d_in[10];
  const float* W_hc = (const float*)d_in[11];
  const float* b_c  = (const float*)d_in[12];
  float* out = (float*)d_out;
  char* ws = (char*)d_ws;

  size_t off = 0;
  auto walloc = [&](size_t sz) { size_t o = off; off = (off + sz + 255) & ~(size_t)255; return o; };
  const size_t o_inbf  = walloc((size_t)TT * BB * DD * 2);   // 64 MB
  const size_t o_WxT   = walloc((size_t)NG * DD * 2);        // 2 MB
  const size_t o_WhT   = walloc((size_t)NG * HH * 2);        // 2 MB
  const size_t o_bias  = walloc((size_t)NG * 4);
  const size_t o_C     = walloc((size_t)BB * HH * 4);
  const size_t o_Hh    = walloc((size_t)TT * BB * HH * 2);   // 64 MB history
  const size_t o_ctl   = walloc(256);
  const size_t o_flags = walloc(8192);
  const size_t o_X     = off;

  const size_t bytes_per_step = (size_t)BB * NG * 2;         // 256 KB
  long spc = (ws_size > o_X) ? (long)((ws_size - o_X) / bytes_per_step) : 0;
  if (spc > TT) spc = TT;
  spc &= ~1L;
  if (spc < 2) spc = 2;

  u16*   inbf  = (u16*)(ws + o_inbf);
  u16*   WxT   = (u16*)(ws + o_WxT);
  u16*   WhT   = (u16*)(ws + o_WhT);
  float* biasp = (float*)(ws + o_bias);
  u16*   Xbuf  = (u16*)(ws + o_X);
  u16*   Hh    = (u16*)(ws + o_Hh);
  float* Cst   = (float*)(ws + o_C);

  k_cast<<<dim3((TT * BB * DD) / 1024), dim3(256), 0, stream>>>(inputs, inbf, (long)TT * BB * DD);
  k_pack<<<dim3(DD), dim3(256), 0, stream>>>(W_xi, W_hi, b_i, W_xf, W_hf, b_f,
                                             W_xo, W_ho, b_o, W_xc, W_hc, b_c,
                                             WxT, WhT, biasp);

  float* doutH = out + (size_t)TT * BB * HH;
  float* doutC = doutH + (size_t)BB * HH;

  for (int t0 = 0; t0 < TT; t0 += (int)spc) {
    int t1 = t0 + (int)spc; if (t1 > TT) t1 = TT;
    const int rows = (t1 - t0) * BB;
    k_gemm_x<<<dim3(NG / 128, rows / 128), dim3(256), 0, stream>>>(
        inbf + (size_t)t0 * BB * DD, WxT, biasp, Xbuf);
    hipMemsetAsync(ws + o_ctl, 0, 256, stream);
    hipMemsetAsync(ws + o_flags, 0, 8192, stream);
    k_lstm<<<dim3(NLW), dim3(512), 0, stream>>>(
        Xbuf, WhT, Hh, Cst, out, doutH, doutC,
        (u32*)(ws + o_ctl), (u32*)(ws + o_flags), t0, t1);
  }
}

// Round 7
// 4379.296 us; speedup vs baseline: 2.3771x; 1.6673x over previous
//
#include <hip/hip_runtime.h>
#include <hip/hip_bf16.h>
#include <stdint.h>

// LSTM (T=1024, B=64, D=512, H=512) on gfx950.
// Phase 1: X[t,b,n] = inputs @ Wx (packed, bf16 MFMA), n = h*4 + gate.
// Phase 2: 8 teams of 8 WGs; team g owns batch rows [8g,8g+8). Teams formed
//   adaptively from HW_REG_XCC_ID. Local teams exchange H through the
//   XCD-shared L2 (plain write-through stores + plain FIRST-TOUCH loads on a
//   per-t history buffer). Arrive/poll: per-step per-GENERATION flag lines --
//   consumer poll iteration g does a first-touch plain load of generation g's
//   128B line (L1 cold miss -> L2 fresh). R5/R6 lesson: sc0 loads hit stale
//   L1 on gfx950; first-touch plain loads are the only fast fresh read.
//   Agent-scope rescue loop after 4 generations guarantees progress under any
//   placement/cache behavior; mixed teams use the proven device-scope path.

typedef float    f32x4  __attribute__((ext_vector_type(4)));
typedef short    s16x8  __attribute__((ext_vector_type(8)));
typedef unsigned short u16;
typedef u16      u16x4  __attribute__((ext_vector_type(4)));
typedef unsigned int u32;

#define TT 1024
#define BB 64
#define DD 512
#define HH 512
#define NG 2048   // 4*HH packed gate columns: n = h*4 + g, g in {i,f,o,c}
#define NTEAM 8
#define NSLOT 8
#define NLW 128   // launched WGs for k_lstm; 64 participate
#define NGEN 4    // first-touch flag generations per step (128B lines)

__device__ __forceinline__ u16 f2bf(float f) {
  __hip_bfloat16 h = __float2bfloat16(f);
  union { __hip_bfloat16 b; u16 u; } v; v.b = h; return v.u;
}
__device__ __forceinline__ float bf2f(u16 u) {
  union { unsigned int i; float f; } v; v.i = ((unsigned int)u) << 16; return v.f;
}
__device__ __forceinline__ float sig_fast(float x) {
  return 1.f / (1.f + __expf(-x));
}
__device__ __forceinline__ float tanh_fast(float x) {
  return 1.f - 2.f / (1.f + __expf(2.f * x));
}

__device__ __forceinline__ void gload_lds16(const u16* g, u16* l) {
  __builtin_amdgcn_global_load_lds(
      (const __attribute__((address_space(1))) unsigned int*)g,
      (__attribute__((address_space(3))) unsigned int*)l, 16, 0, 0);
}

__device__ __forceinline__ void st_plain(u32* p, u32 v) {
  asm volatile("global_store_dword %0, %1, off" :: "v"(p), "v"(v) : "memory");
}
// plain load, compiler can't cache/hoist it (used on first-touch lines only)
__device__ __forceinline__ u32 ld_plain(const u32* p) {
  u32 v;
  asm volatile("global_load_dword %0, %1, off\n\ts_waitcnt vmcnt(0)"
               : "=v"(v) : "v"(p) : "memory");
  return v;
}

// ---------------- setup: cast inputs fp32 -> bf16 ----------------
__global__ void k_cast(const float* __restrict__ in, u16* __restrict__ out, long n) {
  long i = ((long)blockIdx.x * blockDim.x + threadIdx.x) * 4;
  if (i >= n) return;
  const float4 v = *(const float4*)(in + i);
  u16x4 o; o.x = f2bf(v.x); o.y = f2bf(v.y); o.z = f2bf(v.z); o.w = f2bf(v.w);
  *(u16x4*)(out + i) = o;
}

// ---------------- setup: pack weights transposed + gate-interleaved ----------------
__global__ void k_pack(const float* __restrict__ Wxi, const float* __restrict__ Whi, const float* __restrict__ bi,
                       const float* __restrict__ Wxf, const float* __restrict__ Whf, const float* __restrict__ bfi,
                       const float* __restrict__ Wxo, const float* __restrict__ Who, const float* __restrict__ bo,
                       const float* __restrict__ Wxc, const float* __restrict__ Whc, const float* __restrict__ bc,
                       u16* __restrict__ WxT, u16* __restrict__ WhT, float* __restrict__ biasp)
{
  const int k = blockIdx.x;  // 0..511
  const float* Wx[4] = {Wxi, Wxf, Wxo, Wxc};
  const float* Wh[4] = {Whi, Whf, Who, Whc};
  for (int h = threadIdx.x; h < HH; h += blockDim.x) {
#pragma unroll
    for (int g = 0; g < 4; ++g) {
      const long n = h * 4 + g;
      WxT[n * DD + k] = f2bf(Wx[g][(long)k * HH + h]);
      WhT[n * HH + k] = f2bf(Wh[g][(long)k * HH + h]);
    }
  }
  if (k == 0) {
    const float* bp[4] = {bi, bfi, bo, bc};
    for (int n = threadIdx.x; n < NG; n += blockDim.x)
      biasp[n] = bp[n & 3][n >> 2];
  }
}

// ---------------- phase 1: X = A(bf16) @ WxT^T + bias, store bf16 ----------------
__global__ __launch_bounds__(256) void k_gemm_x(
    const u16* __restrict__ A, const u16* __restrict__ BT,
    const float* __restrict__ biasp, u16* __restrict__ X)
{
  __shared__ __align__(16) u16 As[128 * 64];
  __shared__ __align__(16) u16 Bs[128 * 64];
  const int tid = threadIdx.x;
  const int l = tid & 63;
  const int w = tid >> 6;
  const int wr = w >> 1, wc = w & 1;
  const long brow = (long)blockIdx.y * 128;
  const int  bcol = blockIdx.x * 128;
  const int  lr = l >> 3, lc = l & 7;
  const int  cl = l & 15, rg = l >> 4;

  f32x4 acc[4][4];
#pragma unroll
  for (int m = 0; m < 4; ++m)
#pragma unroll
    for (int n = 0; n < 4; ++n) acc[m][n] = (f32x4){0.f, 0.f, 0.f, 0.f};

  for (int k0 = 0; k0 < DD; k0 += 64) {
#pragma unroll
    for (int j = 0; j < 4; ++j) {
      const int sub = w * 4 + j;
      gload_lds16(A  + (brow + sub * 8 + lr) * DD + k0 + lc * 8, &As[sub * 512]);
      gload_lds16(BT + ((long)(bcol + sub * 8 + lr)) * DD + k0 + lc * 8, &Bs[sub * 512]);
    }
    __syncthreads();
#pragma unroll
    for (int kk = 0; kk < 2; ++kk) {
      s16x8 af[4], bfr[4];
#pragma unroll
      for (int m = 0; m < 4; ++m)
        af[m] = *(const s16x8*)&As[(wr * 64 + m * 16 + cl) * 64 + kk * 32 + rg * 8];
#pragma unroll
      for (int n = 0; n < 4; ++n)
        bfr[n] = *(const s16x8*)&Bs[(wc * 64 + n * 16 + cl) * 64 + kk * 32 + rg * 8];
#pragma unroll
      for (int m = 0; m < 4; ++m)
#pragma unroll
        for (int n = 0; n < 4; ++n)
          acc[m][n] = __builtin_amdgcn_mfma_f32_16x16x32_bf16(af[m], bfr[n], acc[m][n], 0, 0, 0);
    }
    __syncthreads();
  }
#pragma unroll
  for (int n = 0; n < 4; ++n) {
    const int col = bcol + wc * 64 + n * 16 + cl;
    const float bv = biasp[col];
#pragma unroll
    for (int m = 0; m < 4; ++m)
#pragma unroll
      for (int j = 0; j < 4; ++j) {
        const long row = brow + wr * 64 + m * 16 + rg * 4 + j;
        X[row * NG + col] = f2bf(acc[m][n][j] + bv);
      }
  }
}

// ---------------- phase 2: team-local recurrent kernel ----------------
__global__ __launch_bounds__(512, 2) void k_lstm(
    const u16* __restrict__ X, const u16* __restrict__ WhT,
    u16* __restrict__ Hh, float* __restrict__ Cst,
    float* __restrict__ dout, float* __restrict__ doutH, float* __restrict__ doutC,
    u32* __restrict__ ctl, u32* __restrict__ flags, int t0, int t1)
{
  __shared__ __align__(16) float pre[8][260];
  __shared__ int s_team, s_slot, s_mixed;
  const int tid = threadIdx.x;

  // ---- adaptive team formation (placement-robust, deadlock-free) ----
  if (tid == 0) {
    u32 x;
    asm volatile("s_getreg_b32 %0, hwreg(HW_REG_XCC_ID)" : "=s"(x));
    x &= 7u;
    u32 r = __hip_atomic_fetch_add(&ctl[x], 1u, __ATOMIC_RELAXED, __HIP_MEMORY_SCOPE_AGENT);
    u32 p = 0;
    if (r >= NSLOT)
      p = __hip_atomic_fetch_add(&ctl[8], 1u, __ATOMIC_RELAXED, __HIP_MEMORY_SCOPE_AGENT);
    __hip_atomic_fetch_add(&ctl[9], 1u, __ATOMIC_RELAXED, __HIP_MEMORY_SCOPE_AGENT);
    while (__hip_atomic_load(&ctl[9], __ATOMIC_RELAXED, __HIP_MEMORY_SCOPE_AGENT) < (u32)NLW)
      __builtin_amdgcn_s_sleep(4);
    u32 c[8];
#pragma unroll
    for (int i = 0; i < 8; ++i)
      c[i] = __hip_atomic_load(&ctl[i], __ATOMIC_RELAXED, __HIP_MEMORY_SCOPE_AGENT);
    int team = -1, slot = 0;
    if (r < NSLOT) { team = (int)x; slot = (int)r; }
    else {
      u32 acc = 0;
      for (int tt = 0; tt < 8; ++tt) {
        u32 have = c[tt] < NSLOT ? c[tt] : NSLOT;
        u32 miss = NSLOT - have;
        if (team < 0 && p < acc + miss) { team = tt; slot = (int)(have + (p - acc)); }
        acc += miss;
      }
    }
    s_team = team; s_slot = slot;
    s_mixed = (team >= 0 && c[team] < NSLOT) ? 1 : 0;
  }
  __syncthreads();
  const int team = s_team, slot = s_slot, mixed = s_mixed;
  if (team < 0) return;

  const int l = tid & 63, wv = tid >> 6;
  const int cl = l & 15, rg = l >> 4;
  const int gcol0 = slot * 256 + wv * 32;   // this wave's gate-col base

  // constant B fragments (registers, loaded once)
  s16x8 bfr[2][16];
#pragma unroll
  for (int nt = 0; nt < 2; ++nt)
#pragma unroll
    for (int ks = 0; ks < 16; ++ks)
      bfr[nt][ks] = *(const s16x8*)&WhT[(long)(gcol0 + nt * 16 + cl) * HH + ks * 32 + rg * 8];

  // pointwise ownership: 1 thread = (row, h)
  const int prow = tid >> 6;               // 0..7  (== wv)
  const int phl  = tid & 63;               // 0..63
  const int grow = team * 8 + prow;        // global batch row
  const int ghl  = slot * 64 + phl;        // global h

  float creg;
  if (t0 == 0) creg = 0.f; else creg = Cst[grow * HH + ghl];

  // flags layout: [team][s][gen][32 u32] -- each gen on its own 128B line
  u32* fteam = flags + (long)team * TT * NGEN * 32;

  for (int t = t0; t < t1; ++t) {
    const int s = t - t0;
    // X for this step (issued before the poll; read-only, no hazard)
    u16x4 xv = *(const u16x4*)&X[((long)s * BB + grow) * NG + slot * 256 + phl * 4];

    if (t > t0) {                           // wait: all team flags for s-1
      if (wv == 0) {
        u32* fstep = fteam + (long)(s - 1) * NGEN * 32;
        u32 vv; unsigned long long b;
        // fast path: first-touch plain loads, one fresh 128B line per gen
        int g = 0;
        for (;;) {
          if (l < NSLOT) vv = ld_plain(fstep + g * 32 + l);
          else vv = 1u;
          b = __ballot(vv != 0);
          if (b == ~0ULL) break;
          ++g;
          if (g >= NGEN) break;
          __builtin_amdgcn_s_sleep(2);      // ~128cy: let producer stores land
        }
        // rescue: agent-scope loads (fresh at MALL), bounded progress
        while (b != ~0ULL) {
          __builtin_amdgcn_s_sleep(8);
          if (l < NSLOT)
            vv = __hip_atomic_load(fstep + l, __ATOMIC_RELAXED,
                                   __HIP_MEMORY_SCOPE_AGENT);
          else vv = 1u;
          b = __ballot(vv != 0);
        }
      }
      __syncthreads();
    }

    f32x4 a0a = (f32x4){0.f,0.f,0.f,0.f}, a0b = (f32x4){0.f,0.f,0.f,0.f};
    f32x4 a1a = (f32x4){0.f,0.f,0.f,0.f}, a1b = (f32x4){0.f,0.f,0.f,0.f};
    if (t > 0) {
      const u16* Hp = Hh + (long)(t - 1) * BB * HH;
      s16x8 af[16];
#pragma unroll
      for (int ks = 0; ks < 16; ++ks) af[ks] = (s16x8){0,0,0,0,0,0,0,0};
      if (cl < 8) {
#pragma unroll
        for (int ks = 0; ks < 16; ++ks)
          af[ks] = *(const s16x8*)&Hp[(team * 8 + cl) * HH + ks * 32 + rg * 8];
      }
#pragma unroll
      for (int ks = 0; ks < 16; ks += 2) {   // 4 independent acc chains
        a0a = __builtin_amdgcn_mfma_f32_16x16x32_bf16(af[ks],     bfr[0][ks],     a0a, 0, 0, 0);
        a1a = __builtin_amdgcn_mfma_f32_16x16x32_bf16(af[ks],     bfr[1][ks],     a1a, 0, 0, 0);
        a0b = __builtin_amdgcn_mfma_f32_16x16x32_bf16(af[ks + 1], bfr[0][ks + 1], a0b, 0, 0, 0);
        a1b = __builtin_amdgcn_mfma_f32_16x16x32_bf16(af[ks + 1], bfr[1][ks + 1], a1b, 0, 0, 0);
      }
    }
    const f32x4 acc0 = a0a + a0b, acc1 = a1a + a1b;
    if (rg < 2) {                            // valid output rows 0..7
#pragma unroll
      for (int j = 0; j < 4; ++j) {
        pre[rg * 4 + j][wv * 32 + cl]      = acc0[j];
        pre[rg * 4 + j][wv * 32 + 16 + cl] = acc1[j];
      }
    }
    __syncthreads();

    // pointwise: 4 gates of one h
    f32x4 pv = *(const f32x4*)&pre[prow][phl * 4];
    const float pi = pv[0] + bf2f((u16)xv.x);
    const float pf = pv[1] + bf2f((u16)xv.y);
    const float po = pv[2] + bf2f((u16)xv.z);
    const float pc = pv[3] + bf2f((u16)xv.w);
    const float ig = sig_fast(pi);
    const float fg = sig_fast(pf);
    const float og = sig_fast(po);
    const float ct = tanh_fast(pc);
    creg = fg * creg + ig * ct;
    const float hv = og * tanh_fast(creg);
    const u16 hb = f2bf(hv);
    u16* hdst = &Hh[((long)t * BB + grow) * HH + ghl];
    if (!mixed) *hdst = hb;
    else asm volatile("global_store_short %0, %1, off sc1"
                      :: "v"(hdst), "v"((u32)hb) : "memory");

    // drain H stores (all waves), then arrive on all NGEN generation lines
    asm volatile("s_waitcnt vmcnt(0)" ::: "memory");
    __syncthreads();
    if (tid == 0) {
      u32* fb = fteam + (long)s * NGEN * 32 + slot;
      if (!mixed) {
#pragma unroll
        for (int g = 0; g < NGEN; ++g) st_plain(fb + g * 32, 1u);
      } else {
#pragma unroll
        for (int g = 0; g < NGEN; ++g)
          __hip_atomic_store(fb + g * 32, 1u, __ATOMIC_RELAXED,
                             __HIP_MEMORY_SCOPE_AGENT);
      }
    }
    // dout off the critical path (drained by next step's vmcnt(0))
    dout[((long)t * BB + grow) * HH + ghl] = hv;
    if (t == TT - 1) {
      doutH[grow * HH + ghl] = hv;
      doutC[grow * HH + ghl] = creg;
    }
  }

  Cst[grow * HH + ghl] = creg;   // plain; flushed at kernel end
}

// ---------------- host ----------------
extern "C" void kernel_launch(void* const* d_in, const int* in_sizes, int n_in,
                              void* d_out, int out_size, void* d_ws, size_t ws_size,
                              hipStream_t stream)
{
  const float* inputs = (const float*)d_in[0];
  const float* W_xi = (const float*)d_in[1];
  const float* W_hi = (const float*)d_in[2];
  const float* b_i  = (const float*)d_in[3];
  const float* W_xf = (const float*)d_in[4];
  const float* W_hf = (const float*)d_in[5];
  const float* b_f  = (const float*)d_in[6];
  const float* W_xo = (const float*)d_in[7];
  const float* W_ho = (const float*)d_in[8];
  const float* b_o  = (const float*)d_in[9];
  const float* W_xc = (const float*)d_in[10];
  const float* W_hc = (const float*)d_in[11];
  const float* b_c  = (const float*)d_in[12];
  float* out = (float*)d_out;
  char* ws = (char*)d_ws;

  size_t off = 0;
  auto walloc = [&](size_t sz) { size_t o = off; off = (off + sz + 255) & ~(size_t)255; return o; };
  const size_t o_inbf  = walloc((size_t)TT * BB * DD * 2);   // 64 MB
  const size_t o_WxT   = walloc((size_t)NG * DD * 2);        // 2 MB
  const size_t o_WhT   = walloc((size_t)NG * HH * 2);        // 2 MB
  const size_t o_bias  = walloc((size_t)NG * 4);
  const size_t o_C     = walloc((size_t)BB * HH * 4);
  const size_t o_Hh    = walloc((size_t)TT * BB * HH * 2);   // 64 MB history
  const size_t o_ctl   = walloc(256);
  const size_t flags_bytes = (size_t)NTEAM * TT * NGEN * 32 * 4;  // 4 MB
  const size_t o_flags = walloc(flags_bytes);
  const size_t o_X     = off;

  const size_t bytes_per_step = (size_t)BB * NG * 2;         // 256 KB
  long spc = (ws_size > o_X) ? (long)((ws_size - o_X) / bytes_per_step) : 0;
  if (spc > TT) spc = TT;
  spc &= ~1L;
  if (spc < 2) spc = 2;

  u16*   inbf  = (u16*)(ws + o_inbf);
  u16*   WxT   = (u16*)(ws + o_WxT);
  u16*   WhT   = (u16*)(ws + o_WhT);
  float* biasp = (float*)(ws + o_bias);
  u16*   Xbuf  = (u16*)(ws + o_X);
  u16*   Hh    = (u16*)(ws + o_Hh);
  float* Cst   = (float*)(ws + o_C);

  k_cast<<<dim3((TT * BB * DD) / 1024), dim3(256), 0, stream>>>(inputs, inbf, (long)TT * BB * DD);
  k_pack<<<dim3(DD), dim3(256), 0, stream>>>(W_xi, W_hi, b_i, W_xf, W_hf, b_f,
                                             W_xo, W_ho, b_o, W_xc, W_hc, b_c,
                                             WxT, WhT, biasp);

  float* doutH = out + (size_t)TT * BB * HH;
  float* doutC = doutH + (size_t)BB * HH;

  for (int t0 = 0; t0 < TT; t0 += (int)spc) {
    int t1 = t0 + (int)spc; if (t1 > TT) t1 = TT;
    const int rows = (t1 - t0) * BB;
    k_gemm_x<<<dim3(NG / 128, rows / 128), dim3(256), 0, stream>>>(
        inbf + (size_t)t0 * BB * DD, WxT, biasp, Xbuf);
    hipMemsetAsync(ws + o_ctl, 0, 256, stream);
    hipMemsetAsync(ws + o_flags, 0, flags_bytes, stream);
    k_lstm<<<dim3(NLW), dim3(512), 0, stream>>>(
        Xbuf, WhT, Hh, Cst, out, doutH, doutC,
        (u32*)(ws + o_ctl), (u32*)(ws + o_flags), t0, t1);
  }
}

// Round 8
// 4130.761 us; speedup vs baseline: 2.5201x; 1.0602x over previous
//
#include <hip/hip_runtime.h>
#include <hip/hip_bf16.h>
#include <stdint.h>

// LSTM (T=1024, B=64, D=512, H=512) on gfx950 — FUSED single launch.
// R7 post-mortem: recurrence protocol is at its cycle floor (~2900cy/step)
// but the chip ran at ~725MHz (DVFS, 97% idle). Fix: one kernel, 256 WGs:
//   blocks 0..63   = R7 team/LSTM WGs (8 teams x 8 slots, XCD-local L2
//                    exchange, first-touch gen flags) + per-chunk X gate.
//   blocks 64..255 = GEMM producer WGs: X tiles in t-order, sc1 stores
//                    (device-visible, no kernel-boundary needed), agent
//                    atomic chunk counters; then become VALU HEATERS so
//                    clocks stay up for the whole recurrence.

typedef float    f32x4  __attribute__((ext_vector_type(4)));
typedef short    s16x8  __attribute__((ext_vector_type(8)));
typedef unsigned short u16;
typedef u16      u16x4  __attribute__((ext_vector_type(4)));
typedef unsigned int u32;

#define TT 1024
#define BB 64
#define DD 512
#define HH 512
#define NG 2048
#define NTEAM 8
#define NSLOT 8
#define NTWG 64        // team WGs (blocks 0..63)
#define NGWG 192       // gemm/heater WGs (blocks 64..255)
#define NGEN 4
#define CHUNK_STEPS 32
#define NCHUNK 32      // TT / CHUNK_STEPS
#define TPC 256        // tiles per chunk: 16 row-tiles x 16 col-tiles
#define NTILES 8192    // total tiles

__device__ __forceinline__ u16 f2bf(float f) {
  __hip_bfloat16 h = __float2bfloat16(f);
  union { __hip_bfloat16 b; u16 u; } v; v.b = h; return v.u;
}
__device__ __forceinline__ float bf2f(u16 u) {
  union { unsigned int i; float f; } v; v.i = ((unsigned int)u) << 16; return v.f;
}
__device__ __forceinline__ float sig_fast(float x) { return 1.f / (1.f + __expf(-x)); }
__device__ __forceinline__ float tanh_fast(float x) { return 1.f - 2.f / (1.f + __expf(2.f * x)); }

__device__ __forceinline__ void gload_lds16(const u16* g, u16* l) {
  __builtin_amdgcn_global_load_lds(
      (const __attribute__((address_space(1))) unsigned int*)g,
      (__attribute__((address_space(3))) unsigned int*)l, 16, 0, 0);
}
__device__ __forceinline__ void st_plain(u32* p, u32 v) {
  asm volatile("global_store_dword %0, %1, off" :: "v"(p), "v"(v) : "memory");
}
__device__ __forceinline__ u32 ld_plain(const u32* p) {
  u32 v;
  asm volatile("global_load_dword %0, %1, off\n\ts_waitcnt vmcnt(0)"
               : "=v"(v) : "v"(p) : "memory");
  return v;
}
__device__ __forceinline__ void st_short_sc1(u16* p, u16 v) {
  asm volatile("global_store_short %0, %1, off sc1" :: "v"(p), "v"((u32)v) : "memory");
}

// ---------------- setup kernels (unchanged) ----------------
__global__ void k_cast(const float* __restrict__ in, u16* __restrict__ out, long n) {
  long i = ((long)blockIdx.x * blockDim.x + threadIdx.x) * 4;
  if (i >= n) return;
  const float4 v = *(const float4*)(in + i);
  u16x4 o; o.x = f2bf(v.x); o.y = f2bf(v.y); o.z = f2bf(v.z); o.w = f2bf(v.w);
  *(u16x4*)(out + i) = o;
}

__global__ void k_pack(const float* __restrict__ Wxi, const float* __restrict__ Whi, const float* __restrict__ bi,
                       const float* __restrict__ Wxf, const float* __restrict__ Whf, const float* __restrict__ bfi,
                       const float* __restrict__ Wxo, const float* __restrict__ Who, const float* __restrict__ bo,
                       const float* __restrict__ Wxc, const float* __restrict__ Whc, const float* __restrict__ bc,
                       u16* __restrict__ WxT, u16* __restrict__ WhT, float* __restrict__ biasp)
{
  const int k = blockIdx.x;
  const float* Wx[4] = {Wxi, Wxf, Wxo, Wxc};
  const float* Wh[4] = {Whi, Whf, Who, Whc};
  for (int h = threadIdx.x; h < HH; h += blockDim.x) {
#pragma unroll
    for (int g = 0; g < 4; ++g) {
      const long n = h * 4 + g;
      WxT[n * DD + k] = f2bf(Wx[g][(long)k * HH + h]);
      WhT[n * HH + k] = f2bf(Wh[g][(long)k * HH + h]);
    }
  }
  if (k == 0) {
    const float* bp[4] = {bi, bfi, bo, bc};
    for (int n = threadIdx.x; n < NG; n += blockDim.x)
      biasp[n] = bp[n & 3][n >> 2];
  }
}

// ---------------- fused kernel ----------------
__global__ __launch_bounds__(512, 2) void k_fused(
    const u16* __restrict__ inbf, const u16* __restrict__ WxT,
    const u16* __restrict__ WhT, const float* __restrict__ biasp,
    u16* __restrict__ X, u16* __restrict__ Hh, float* __restrict__ Cst,
    float* __restrict__ dout, float* __restrict__ doutH, float* __restrict__ doutC,
    u32* __restrict__ ctl, u32* __restrict__ flags, u32* __restrict__ cnt)
{
  __shared__ __align__(16) u16 As[128 * 64];
  __shared__ __align__(16) u16 Bs[128 * 64];
  __shared__ __align__(16) float pre[8][260];
  __shared__ int s_team, s_slot, s_mixed;
  const int tid = threadIdx.x;
  const int role = blockIdx.x;
  const int l = tid & 63, wv = tid >> 6;

  if (role >= NTWG) {
    // ================= GEMM producer + heater =================
    const int gwg = role - NTWG;
    const int wr = wv >> 2, wc = wv & 3;       // 2x4 wave grid
    const int lr = l >> 3, lc = l & 7;
    const int cl = l & 15, rg = l >> 4;

    for (int tile = gwg; tile < NTILES; tile += NGWG) {
      const int c = tile >> 8, q = tile & 255;
      const long brow = (long)(c * 16 + (q >> 4)) * 128;
      const int  bcol = (q & 15) * 128;

      f32x4 acc[4][2];
#pragma unroll
      for (int m = 0; m < 4; ++m)
#pragma unroll
        for (int n = 0; n < 2; ++n) acc[m][n] = (f32x4){0.f, 0.f, 0.f, 0.f};

      for (int k0 = 0; k0 < DD; k0 += 64) {
#pragma unroll
        for (int j = 0; j < 2; ++j) {
          const int sub = wv * 2 + j;          // 0..15, 8 rows each
          gload_lds16(inbf + (brow + sub * 8 + lr) * DD + k0 + lc * 8, &As[sub * 512]);
          gload_lds16(WxT  + ((long)(bcol + sub * 8 + lr)) * DD + k0 + lc * 8, &Bs[sub * 512]);
        }
        __syncthreads();
#pragma unroll
        for (int kk = 0; kk < 2; ++kk) {
          s16x8 af[4], bfx[2];
#pragma unroll
          for (int m = 0; m < 4; ++m)
            af[m] = *(const s16x8*)&As[(wr * 64 + m * 16 + cl) * 64 + kk * 32 + rg * 8];
#pragma unroll
          for (int n = 0; n < 2; ++n)
            bfx[n] = *(const s16x8*)&Bs[(wc * 32 + n * 16 + cl) * 64 + kk * 32 + rg * 8];
#pragma unroll
          for (int m = 0; m < 4; ++m)
#pragma unroll
            for (int n = 0; n < 2; ++n)
              acc[m][n] = __builtin_amdgcn_mfma_f32_16x16x32_bf16(af[m], bfx[n], acc[m][n], 0, 0, 0);
        }
        __syncthreads();
      }
#pragma unroll
      for (int n = 0; n < 2; ++n) {
        const int col = bcol + wc * 32 + n * 16 + cl;
        const float bv = biasp[col];
#pragma unroll
        for (int m = 0; m < 4; ++m)
#pragma unroll
          for (int j = 0; j < 4; ++j) {
            const long row = brow + wr * 64 + m * 16 + rg * 4 + j;
            st_short_sc1(&X[row * NG + col], f2bf(acc[m][n][j] + bv));
          }
      }
      asm volatile("s_waitcnt vmcnt(0)" ::: "memory");
      __syncthreads();
      if (tid == 0)
        __hip_atomic_fetch_add(&cnt[c * 32], 1u, __ATOMIC_RELAXED, __HIP_MEMORY_SCOPE_AGENT);
      __syncthreads();
    }
    // ---- heater: keep clocks up until all teams finish ----
    float hacc = 1.0f + (float)tid;
    int it2 = 0;
    for (;;) {
#pragma unroll
      for (int u = 0; u < 64; ++u) hacc = __builtin_fmaf(hacc, 1.0000001f, 1.0e-7f);
      asm volatile("" :: "v"(hacc));
      if ((++it2 & 63) == 0) {
        if (__hip_atomic_load(&ctl[16], __ATOMIC_RELAXED, __HIP_MEMORY_SCOPE_AGENT) >= (u32)NTWG)
          break;
      }
    }
    return;
  }

  // ================= team / LSTM WGs (R7 protocol, unchanged core) =================
  if (tid == 0) {
    u32 x;
    asm volatile("s_getreg_b32 %0, hwreg(HW_REG_XCC_ID)" : "=s"(x));
    x &= 7u;
    u32 r = __hip_atomic_fetch_add(&ctl[x], 1u, __ATOMIC_RELAXED, __HIP_MEMORY_SCOPE_AGENT);
    u32 p = 0;
    if (r >= NSLOT)
      p = __hip_atomic_fetch_add(&ctl[8], 1u, __ATOMIC_RELAXED, __HIP_MEMORY_SCOPE_AGENT);
    __hip_atomic_fetch_add(&ctl[9], 1u, __ATOMIC_RELAXED, __HIP_MEMORY_SCOPE_AGENT);
    while (__hip_atomic_load(&ctl[9], __ATOMIC_RELAXED, __HIP_MEMORY_SCOPE_AGENT) < (u32)NTWG)
      __builtin_amdgcn_s_sleep(4);
    u32 c[8];
#pragma unroll
    for (int i = 0; i < 8; ++i)
      c[i] = __hip_atomic_load(&ctl[i], __ATOMIC_RELAXED, __HIP_MEMORY_SCOPE_AGENT);
    int team = -1, slot = 0;
    if (r < NSLOT) { team = (int)x; slot = (int)r; }
    else {
      u32 acc = 0;
      for (int tt = 0; tt < 8; ++tt) {
        u32 have = c[tt] < NSLOT ? c[tt] : NSLOT;
        u32 miss = NSLOT - have;
        if (team < 0 && p < acc + miss) { team = tt; slot = (int)(have + (p - acc)); }
        acc += miss;
      }
    }
    s_team = team; s_slot = slot;
    s_mixed = (team >= 0 && c[team] < NSLOT) ? 1 : 0;
  }
  __syncthreads();
  const int team = s_team, slot = s_slot, mixed = s_mixed;
  if (team < 0) return;

  const int cl = l & 15, rg = l >> 4;
  const int gcol0 = slot * 256 + wv * 32;

  s16x8 bfr[2][16];
#pragma unroll
  for (int nt = 0; nt < 2; ++nt)
#pragma unroll
    for (int ks = 0; ks < 16; ++ks)
      bfr[nt][ks] = *(const s16x8*)&WhT[(long)(gcol0 + nt * 16 + cl) * HH + ks * 32 + rg * 8];

  const int prow = tid >> 6;
  const int phl  = tid & 63;
  const int grow = team * 8 + prow;
  const int ghl  = slot * 64 + phl;

  float creg = 0.f;
  u32* fteam = flags + (long)team * TT * NGEN * 32;

  for (int c = 0; c < NCHUNK; ++c) {
    // gate: X chunk c complete (TPC tiles)
    if (tid == 0) {
      while (__hip_atomic_load(&cnt[c * 32], __ATOMIC_RELAXED, __HIP_MEMORY_SCOPE_AGENT) < (u32)TPC)
        __builtin_amdgcn_s_sleep(16);
    }
    __syncthreads();

    for (int t = c * CHUNK_STEPS; t < (c + 1) * CHUNK_STEPS; ++t) {
      u16x4 xv = *(const u16x4*)&X[((long)t * BB + grow) * NG + slot * 256 + phl * 4];

      if (t > 0) {
        if (wv == 0) {
          u32* fstep = fteam + (long)(t - 1) * NGEN * 32;
          u32 vv; unsigned long long b;
          int g = 0;
          for (;;) {
            if (l < NSLOT) vv = ld_plain(fstep + g * 32 + l);
            else vv = 1u;
            b = __ballot(vv != 0);
            if (b == ~0ULL) break;
            ++g;
            if (g >= NGEN) break;
            __builtin_amdgcn_s_sleep(2);
          }
          while (b != ~0ULL) {
            __builtin_amdgcn_s_sleep(8);
            if (l < NSLOT)
              vv = __hip_atomic_load(fstep + l, __ATOMIC_RELAXED, __HIP_MEMORY_SCOPE_AGENT);
            else vv = 1u;
            b = __ballot(vv != 0);
          }
        }
        __syncthreads();
      }

      f32x4 a0a = (f32x4){0.f,0.f,0.f,0.f}, a0b = (f32x4){0.f,0.f,0.f,0.f};
      f32x4 a1a = (f32x4){0.f,0.f,0.f,0.f}, a1b = (f32x4){0.f,0.f,0.f,0.f};
      if (t > 0) {
        const u16* Hp = Hh + (long)(t - 1) * BB * HH;
        s16x8 af[16];
#pragma unroll
        for (int ks = 0; ks < 16; ++ks) af[ks] = (s16x8){0,0,0,0,0,0,0,0};
        if (cl < 8) {
#pragma unroll
          for (int ks = 0; ks < 16; ++ks)
            af[ks] = *(const s16x8*)&Hp[(team * 8 + cl) * HH + ks * 32 + rg * 8];
        }
#pragma unroll
        for (int ks = 0; ks < 16; ks += 2) {
          a0a = __builtin_amdgcn_mfma_f32_16x16x32_bf16(af[ks],     bfr[0][ks],     a0a, 0, 0, 0);
          a1a = __builtin_amdgcn_mfma_f32_16x16x32_bf16(af[ks],     bfr[1][ks],     a1a, 0, 0, 0);
          a0b = __builtin_amdgcn_mfma_f32_16x16x32_bf16(af[ks + 1], bfr[0][ks + 1], a0b, 0, 0, 0);
          a1b = __builtin_amdgcn_mfma_f32_16x16x32_bf16(af[ks + 1], bfr[1][ks + 1], a1b, 0, 0, 0);
        }
      }
      const f32x4 acc0 = a0a + a0b, acc1 = a1a + a1b;
      if (rg < 2) {
#pragma unroll
        for (int j = 0; j < 4; ++j) {
          pre[rg * 4 + j][wv * 32 + cl]      = acc0[j];
          pre[rg * 4 + j][wv * 32 + 16 + cl] = acc1[j];
        }
      }
      __syncthreads();

      f32x4 pv = *(const f32x4*)&pre[prow][phl * 4];
      const float pi = pv[0] + bf2f((u16)xv.x);
      const float pf = pv[1] + bf2f((u16)xv.y);
      const float po = pv[2] + bf2f((u16)xv.z);
      const float pc = pv[3] + bf2f((u16)xv.w);
      const float ig = sig_fast(pi);
      const float fg = sig_fast(pf);
      const float og = sig_fast(po);
      const float ct = tanh_fast(pc);
      creg = fg * creg + ig * ct;
      const float hv = og * tanh_fast(creg);
      const u16 hb = f2bf(hv);
      u16* hdst = &Hh[((long)t * BB + grow) * HH + ghl];
      if (!mixed) *hdst = hb;
      else asm volatile("global_store_short %0, %1, off sc1"
                        :: "v"(hdst), "v"((u32)hb) : "memory");

      asm volatile("s_waitcnt vmcnt(0)" ::: "memory");
      __syncthreads();
      if (tid == 0) {
        u32* fb = fteam + (long)t * NGEN * 32 + slot;
        if (!mixed) {
#pragma unroll
          for (int g = 0; g < NGEN; ++g) st_plain(fb + g * 32, 1u);
        } else {
#pragma unroll
          for (int g = 0; g < NGEN; ++g)
            __hip_atomic_store(fb + g * 32, 1u, __ATOMIC_RELAXED, __HIP_MEMORY_SCOPE_AGENT);
        }
      }
      dout[((long)t * BB + grow) * HH + ghl] = hv;
      if (t == TT - 1) {
        doutH[grow * HH + ghl] = hv;
        doutC[grow * HH + ghl] = creg;
      }
    }
  }

  Cst[grow * HH + ghl] = creg;
  __syncthreads();
  if (tid == 0)
    __hip_atomic_fetch_add(&ctl[16], 1u, __ATOMIC_RELAXED, __HIP_MEMORY_SCOPE_AGENT);
}

// ---------------- host ----------------
extern "C" void kernel_launch(void* const* d_in, const int* in_sizes, int n_in,
                              void* d_out, int out_size, void* d_ws, size_t ws_size,
                              hipStream_t stream)
{
  const float* inputs = (const float*)d_in[0];
  const float* W_xi = (const float*)d_in[1];
  const float* W_hi = (const float*)d_in[2];
  const float* b_i  = (const float*)d_in[3];
  const float* W_xf = (const float*)d_in[4];
  const float* W_hf = (const float*)d_in[5];
  const float* b_f  = (const float*)d_in[6];
  const float* W_xo = (const float*)d_in[7];
  const float* W_ho = (const float*)d_in[8];
  const float* b_o  = (const float*)d_in[9];
  const float* W_xc = (const float*)d_in[10];
  const float* W_hc = (const float*)d_in[11];
  const float* b_c  = (const float*)d_in[12];
  float* out = (float*)d_out;
  char* ws = (char*)d_ws;

  size_t off = 0;
  auto walloc = [&](size_t sz) { size_t o = off; off = (off + sz + 255) & ~(size_t)255; return o; };
  const size_t o_inbf  = walloc((size_t)TT * BB * DD * 2);   // 64 MB
  const size_t o_WxT   = walloc((size_t)NG * DD * 2);
  const size_t o_WhT   = walloc((size_t)NG * HH * 2);
  const size_t o_bias  = walloc((size_t)NG * 4);
  const size_t o_C     = walloc((size_t)BB * HH * 4);
  const size_t o_Hh    = walloc((size_t)TT * BB * HH * 2);   // 64 MB
  const size_t o_ctl   = walloc(256);
  const size_t flags_bytes = (size_t)NTEAM * TT * NGEN * 32 * 4;  // 4 MB
  const size_t o_flags = walloc(flags_bytes);
  const size_t o_cnt   = walloc((size_t)NCHUNK * 32 * 4);
  const size_t o_X     = walloc((size_t)TT * BB * NG * 2);   // 256 MB

  u16*   inbf  = (u16*)(ws + o_inbf);
  u16*   WxT   = (u16*)(ws + o_WxT);
  u16*   WhT   = (u16*)(ws + o_WhT);
  float* biasp = (float*)(ws + o_bias);
  u16*   Xbuf  = (u16*)(ws + o_X);
  u16*   Hh    = (u16*)(ws + o_Hh);
  float* Cst   = (float*)(ws + o_C);

  k_cast<<<dim3((TT * BB * DD) / 1024), dim3(256), 0, stream>>>(inputs, inbf, (long)TT * BB * DD);
  k_pack<<<dim3(DD), dim3(256), 0, stream>>>(W_xi, W_hi, b_i, W_xf, W_hf, b_f,
                                             W_xo, W_ho, b_o, W_xc, W_hc, b_c,
                                             WxT, WhT, biasp);

  float* doutH = out + (size_t)TT * BB * HH;
  float* doutC = doutH + (size_t)BB * HH;

  hipMemsetAsync(ws + o_ctl, 0, 256, stream);
  hipMemsetAsync(ws + o_flags, 0, flags_bytes, stream);
  hipMemsetAsync(ws + o_cnt, 0, (size_t)NCHUNK * 32 * 4, stream);

  k_fused<<<dim3(NTWG + NGWG), dim3(512), 0, stream>>>(
      inbf, WxT, WhT, biasp, Xbuf, Hh, Cst, out, doutH, doutC,
      (u32*)(ws + o_ctl), (u32*)(ws + o_flags), (u32*)(ws + o_cnt));
}